// Round 5
// baseline (100.515 us; speedup 1.0000x reference)
//
#include <hip/hip_runtime.h>

#define NPTS 384
#define DIMS 256
#define TI 6       // i-rows per block in phase 2
#define JC 48      // j-columns per block in phase 2
#define NW 6       // waves per block (384 threads)
#define NBLK 512   // 64 i-blocks x 8 j-blocks (phase 2)
#define NTILES 288 // 12x12 tiles x 2 matrices (phase 1)

// ---------------------------------------------------------------------------
// Kernel 1: fused Gram + diagonal + pack. 288 blocks x 384 threads: one 32x32
// tile of one matrix (student/teacher) per block. The 8 k-chunks are split
// across the 6 waves; each wave stages into its OWN LDS buffer (wave-private,
// no inter-wave barriers in the k-loop; same-wave LDS RAW made explicit with
// s_waitcnt lgkmcnt(0)). Partial 4x4 accs + diagonal partials are combined by
// wave 0 after one __syncthreads.
// Outputs:
//   P4[i][j] = { gs_ii - gs_ij, rs_ij, gt_ii - gt_ij, rt_ij }  (float4)
//   W2[i][j] = { gs_ij, gt_ij }                                (float2)
// r == 0 on the diagonal (masks j==i / k==i exactly, as in the reference).
// Student/teacher blocks write disjoint halves of each P4/W2 element.
// Block 0 also zeroes out[0] (replaces a memset dispatch).
// ---------------------------------------------------------------------------
__global__ __launch_bounds__(NPTS) void gram_pack_kernel(
        const float* __restrict__ Es, const float* __restrict__ Et,
        float4* __restrict__ P4, float2* __restrict__ W2,
        float* __restrict__ out) {
    __shared__ float SA[NW][32][36];   // 27648 B
    __shared__ float SB[NW][32][36];   // 27648 B
    __shared__ float dpart[NW][64];    //  1536 B
    __shared__ float dAB[64];          //   256 B  (~57 KB -> 2 blocks/CU)

    const int tid  = threadIdx.x;      // 0..383
    const int w    = tid >> 6;         // wave 0..5
    const int lane = tid & 63;

    if (blockIdx.x == 0 && tid == 0) out[0] = 0.0f;

    const int tb  = blockIdx.x;
    const int z   = tb / 144;          // 0 = student, 1 = teacher
    const int rem = tb - z * 144;
    const int ti  = rem / 12;
    const int tj  = rem - ti * 12;
    const int i0  = ti * 32;
    const int j0  = tj * 32;
    const float* __restrict__ E = z ? Et : Es;

    const int tx = lane & 7;           // 0..7
    const int ty = lane >> 3;          // 0..7
    const int e  = lane & 31;
    // diagonal source: column e of this wave's SA (lanes 0..31 -> i-rows)
    // or SB (lanes 32..63 -> j-rows); float stride 36.
    const float* dsrc = (lane < 32) ? &SA[w][0][e] : &SB[w][0][e];

    float acc[4][4] = {};
    float dsum = 0.0f;

    for (int c = w; c < 8; c += NW) {  // waves 0,1: 2 chunks; 2..5: 1 chunk
        const int k0 = c * 32;
        // stage 32x32 A/B tiles, transposed k-major, wave-private buffers
#pragma unroll
        for (int m = 0; m < 4; m++) {
            const int row = ty + 8 * m;
            float va[4], vb[4];
            *(float4*)va = *(const float4*)&E[(i0 + row) * DIMS + k0 + 4 * tx];
            *(float4*)vb = *(const float4*)&E[(j0 + row) * DIMS + k0 + 4 * tx];
#pragma unroll
            for (int q = 0; q < 4; q++) {
                SA[w][4 * tx + q][row] = va[q];
                SB[w][4 * tx + q][row] = vb[q];
            }
        }
        // same-wave cross-lane LDS RAW: make the writes visible before reads
        asm volatile("s_waitcnt lgkmcnt(0)" ::: "memory");

        // 4x4 micro-tile FMA from wave-private LDS (ds_read_b128)
#pragma unroll
        for (int kk = 0; kk < 32; kk++) {
            float a[4], b[4];
            *(float4*)a = *(const float4*)&SA[w][kk][4 * ty];
            *(float4*)b = *(const float4*)&SB[w][kk][4 * tx];
#pragma unroll
            for (int p = 0; p < 4; p++)
#pragma unroll
                for (int q = 0; q < 4; q++)
                    acc[p][q] = fmaf(a[p], b[q], acc[p][q]);
        }
        // diagonal partial for this chunk (before the buffer is overwritten)
#pragma unroll
        for (int kk = 0; kk < 32; kk++) {
            float v = dsrc[kk * 36];
            dsum = fmaf(v, v, dsum);
        }
        asm volatile("s_waitcnt lgkmcnt(0)" ::: "memory");  // reads done before re-stage
    }

    // publish partials: acc -> this wave's SA buffer (flat), dsum -> dpart
    {
        float* pb = &SA[w][0][0];
#pragma unroll
        for (int p = 0; p < 4; p++)
            *(float4*)&pb[lane * 16 + 4 * p] =
                make_float4(acc[p][0], acc[p][1], acc[p][2], acc[p][3]);
        dpart[w][lane] = dsum;
    }
    __syncthreads();

    if (w == 0) {
#pragma unroll
        for (int ww = 1; ww < NW; ww++) {
            const float* qb = &SA[ww][0][0];
#pragma unroll
            for (int p = 0; p < 4; p++) {
                float4 v = *(const float4*)&qb[lane * 16 + 4 * p];
                acc[p][0] += v.x; acc[p][1] += v.y;
                acc[p][2] += v.z; acc[p][3] += v.w;
            }
        }
        float dtot = 0.0f;
#pragma unroll
        for (int ww = 0; ww < NW; ww++) dtot += dpart[ww][lane];
        dAB[lane] = dtot;              // [0..31]=g_ii (i-rows), [32..63]=g_jj
        // wave 0 wrote and reads dAB itself; in-wave order + waitcnt suffices
        asm volatile("s_waitcnt lgkmcnt(0)" ::: "memory");

        // pack epilogue: 4x4 outputs per lane; z selects which half of each
        // float4/float2 this block owns -- disjoint bytes, no race.
#pragma unroll
        for (int p = 0; p < 4; p++) {
            const int i     = i0 + 4 * ty + p;
            const float dAv = dAB[4 * ty + p];
#pragma unroll
            for (int q = 0; q < 4; q++) {
                const int j     = j0 + 4 * tx + q;
                const float g   = acc[p][q];
                const float dBv = dAB[32 + 4 * tx + q];
                float v = fmaxf(dAv - 2.0f * g + dBv, 0.0f);
                float r = (i == j) ? 0.0f : 1.0f / fmaxf(sqrtf(v), 1e-12f);
                float* dstP = (float*)&P4[i * NPTS + j];
                float* dstW = (float*)&W2[i * NPTS + j];
                *(float2*)(dstP + 2 * z) = make_float2(dAv - g, r);
                dstW[z] = g;
            }
        }
    }
}

// ---------------------------------------------------------------------------
// Kernel 2: triple-loop reduction. 512 blocks x 384 threads (thread == k).
// Per-(i,j) data via ONE wave-uniform (scalarizable s_load_dwordx4) P4 load;
// per-k data via ONE coalesced 8B W2 load. One atomic per block.
// angle_ijk = r_ij * fma(r_ik, G_jk + (G_ii - G_ij), -r_ik*G_ik)
// huber(x)  = m*(x - 0.5m), m = min(|x|,1)   (branch-free, exact)
// ---------------------------------------------------------------------------
__global__ __launch_bounds__(NPTS) void rkd_angle_kernel(
        const float4* __restrict__ P4, const float2* __restrict__ W2,
        float* __restrict__ out) {
    const int k  = threadIdx.x;              // 0..383
    const int i0 = (blockIdx.x >> 3) * TI;   // 64 i-blocks
    const int j0 = (blockIdx.x & 7) * JC;    //  8 j-blocks

    float rsk[TI], rtk[TI], nqs[TI], nqt[TI];
#pragma unroll
    for (int r = 0; r < TI; r++) {
        float4 pk = P4[(i0 + r) * NPTS + k];   // coalesced 16B
        float2 wk = W2[(i0 + r) * NPTS + k];   // coalesced 8B
        rsk[r] = pk.y;
        rtk[r] = pk.w;
        nqs[r] = -(pk.y * wk.x);
        nqt[r] = -(pk.w * wk.y);
    }

    float acc = 0.0f;
#pragma unroll 2
    for (int j = j0; j < j0 + JC; j++) {
        float2 wv = W2[j * NPTS + k];          // coalesced {gs_jk, gt_jk}
#pragma unroll
        for (int r = 0; r < TI; r++) {
            float4 pj = P4[(i0 + r) * NPTS + j];  // wave-uniform -> s_load_dwordx4
            float as = pj.y * fmaf(rsk[r], wv.x + pj.x, nqs[r]);
            float at = pj.w * fmaf(rtk[r], wv.y + pj.z, nqt[r]);
            float d  = as - at;
            float ad = fabsf(d);
            float m  = fminf(ad, 1.0f);
            acc = fmaf(m, fmaf(-0.5f, m, ad), acc);
        }
    }

    // wave reduce (64-wide), then block reduce, one atomic per block
#pragma unroll
    for (int off = 32; off > 0; off >>= 1)
        acc += __shfl_down(acc, off, 64);

    __shared__ float wsum[NW];
    const int w = k >> 6, lane = k & 63;
    if (lane == 0) wsum[w] = acc;
    __syncthreads();
    if (k == 0) {
        float s = 0.0f;
#pragma unroll
        for (int ww = 0; ww < NW; ww++) s += wsum[ww];
        atomicAdd(out, s * (1.0f / (384.0f * 384.0f * 384.0f)));
    }
}

extern "C" void kernel_launch(void* const* d_in, const int* in_sizes, int n_in,
                              void* d_out, int out_size, void* d_ws, size_t ws_size,
                              hipStream_t stream) {
    const float* student = (const float*)d_in[0];
    const float* teacher = (const float*)d_in[1];
    float* out = (float*)d_out;

    // workspace: P4 (NPTS*NPTS float4, 2.25 MiB) + W2 (NPTS*NPTS float2, 1.125 MiB)
    float4* P4 = (float4*)d_ws;
    float2* W2 = (float2*)(P4 + NPTS * NPTS);

    gram_pack_kernel<<<dim3(NTILES), NPTS, 0, stream>>>(student, teacher, P4, W2, out);
    rkd_angle_kernel<<<dim3(NBLK), NPTS, 0, stream>>>(P4, W2, out);
}

// Round 6
// 97.028 us; speedup vs baseline: 1.0359x; 1.0359x over previous
//
#include <hip/hip_runtime.h>

#define NPTS 384
#define DIMS 256
#define TI 6      // i-rows per block in main kernel
#define JC 24     // j-columns per block in main kernel

// ---------------------------------------------------------------------------
// Kernel 1: fused Gram + diagonal + pack (round-2 structure, P4/W2 layout).
// grid (12,12,2): one 32x32 tile of one matrix (z: student/teacher) per
// 64-thread (1-wave) block, 4x4 micro-tile per thread. LDS k-major
// (transposed) so fragments come via ds_read_b128. Diagonal ||e||^2 terms are
// accumulated from the staged tiles (lanes 0..31: i-rows from AsT, lanes
// 32..63: j-rows from BsT) -- no cross-block data needed.
// Outputs (interleaved so phase 2 needs ONE load per datum):
//   P4[i][j] = { gs_ii - gs_ij, rs_ij, gt_ii - gt_ij, rt_ij }  (float4)
//   W2[i][j] = { gs_ij, gt_ij }                                (float2)
// z==0 writes the first 8B/4B half of each element, z==1 the second half --
// disjoint bytes, no race. r == 0 on the diagonal (masks j==i / k==i exactly).
// Block (0,0,0) also zeroes out[0] (replaces the memset dispatch).
// ---------------------------------------------------------------------------
__global__ __launch_bounds__(64) void gram_pack_kernel(
        const float* __restrict__ Es, const float* __restrict__ Et,
        float4* __restrict__ P4, float2* __restrict__ W2,
        float* __restrict__ out) {
    const int z = blockIdx.z;                 // 0 = student, 1 = teacher
    const float* __restrict__ E = z ? Et : Es;

    if (blockIdx.x == 0 && blockIdx.y == 0 && z == 0 && threadIdx.x == 0)
        out[0] = 0.0f;

    __shared__ float AsT[32][36];
    __shared__ float BsT[32][36];
    __shared__ float dA[32];
    __shared__ float dB[32];

    const int t  = threadIdx.x;      // 0..63
    const int tx = t & 7;            // 0..7
    const int ty = t >> 3;           // 0..7
    const int i0 = blockIdx.x * 32;
    const int j0 = blockIdx.y * 32;

    // this thread's diagonal entry: column e of AsT (t<32) or BsT (t>=32)
    const int e = t & 31;
    const float* dsrc = (t < 32) ? &AsT[0][e] : &BsT[0][e];   // stride 36 floats
    float dsum = 0.0f;

    float acc[4][4] = {};

    for (int k0 = 0; k0 < DIMS; k0 += 32) {
        // stage 32x32 A/B tiles, transposed into k-major LDS
#pragma unroll
        for (int m = 0; m < 4; m++) {
            const int row = ty + 8 * m;
            float va[4], vb[4];
            *(float4*)va = *(const float4*)&E[(i0 + row) * DIMS + k0 + 4 * tx];
            *(float4*)vb = *(const float4*)&E[(j0 + row) * DIMS + k0 + 4 * tx];
#pragma unroll
            for (int q = 0; q < 4; q++) {
                AsT[4 * tx + q][row] = va[q];
                BsT[4 * tx + q][row] = vb[q];
            }
        }
        __syncthreads();
#pragma unroll
        for (int k = 0; k < 32; k++) {
            float a[4], b[4];
            *(float4*)a = *(const float4*)&AsT[k][4 * ty];
            *(float4*)b = *(const float4*)&BsT[k][4 * tx];
#pragma unroll
            for (int p = 0; p < 4; p++)
#pragma unroll
                for (int q = 0; q < 4; q++)
                    acc[p][q] = fmaf(a[p], b[q], acc[p][q]);
        }
        // diagonal partial for this chunk (lane-consecutive -> conflict-free)
#pragma unroll
        for (int k = 0; k < 32; k++) {
            float v = dsrc[k * 36];
            dsum = fmaf(v, v, dsum);
        }
        __syncthreads();
    }

    if (t < 32) dA[e] = dsum; else dB[e] = dsum;
    __syncthreads();

    // pack epilogue: 4x4 outputs per thread; z selects which half of each
    // P4/W2 element this block owns (disjoint bytes).
#pragma unroll
    for (int p = 0; p < 4; p++) {
        const int i     = i0 + 4 * ty + p;
        const float dAv = dA[4 * ty + p];
#pragma unroll
        for (int q = 0; q < 4; q++) {
            const int j     = j0 + 4 * tx + q;
            const float g   = acc[p][q];
            const float dBv = dB[4 * tx + q];
            float v = fmaxf(dAv - 2.0f * g + dBv, 0.0f);
            float r = (i == j) ? 0.0f : 1.0f / fmaxf(sqrtf(v), 1e-12f);
            float* dstP = (float*)&P4[i * NPTS + j];
            float* dstW = (float*)&W2[i * NPTS + j];
            *(float2*)(dstP + 2 * z) = make_float2(dAv - g, r);
            dstW[z] = g;
        }
    }
}

// ---------------------------------------------------------------------------
// Kernel 2: triple-loop reduction (round-2 geometry: TI=6, JC=24, 1024 blocks
// = 24 waves/CU for latency hiding). 384 threads, thread == k.
// Per-(i,j) data via ONE wave-uniform (scalarizable s_load_dwordx4) P4 load;
// per-k data via ONE coalesced 8B W2 load. One atomic per block.
// angle_ijk = r_ij * fma(r_ik, G_jk + (G_ii - G_ij), -r_ik*G_ik)
// huber(x)  = m*(x - 0.5m), m = min(|x|,1)   (branch-free, exact)
// ---------------------------------------------------------------------------
__global__ __launch_bounds__(NPTS) void rkd_angle_kernel(
        const float4* __restrict__ P4, const float2* __restrict__ W2,
        float* __restrict__ out) {
    const int k  = threadIdx.x;            // 0..383
    const int i0 = blockIdx.x * TI;        // 64 i-blocks
    const int j0 = blockIdx.y * JC;        // 16 j-blocks

    float rsk[TI], rtk[TI], nqs[TI], nqt[TI];
#pragma unroll
    for (int r = 0; r < TI; r++) {
        float4 pk = P4[(i0 + r) * NPTS + k];   // coalesced 16B
        float2 wk = W2[(i0 + r) * NPTS + k];   // coalesced 8B
        rsk[r] = pk.y;
        rtk[r] = pk.w;
        nqs[r] = -(pk.y * wk.x);
        nqt[r] = -(pk.w * wk.y);
    }

    float acc = 0.0f;
#pragma unroll 2
    for (int j = j0; j < j0 + JC; j++) {
        float2 wv = W2[j * NPTS + k];          // coalesced {gs_jk, gt_jk}
#pragma unroll
        for (int r = 0; r < TI; r++) {
            float4 pj = P4[(i0 + r) * NPTS + j];  // wave-uniform -> s_load_dwordx4
            float as = pj.y * fmaf(rsk[r], wv.x + pj.x, nqs[r]);
            float at = pj.w * fmaf(rtk[r], wv.y + pj.z, nqt[r]);
            float d  = as - at;
            float ad = fabsf(d);
            float m  = fminf(ad, 1.0f);
            acc = fmaf(m, fmaf(-0.5f, m, ad), acc);
        }
    }

    // wave reduce (64-wide), then block reduce, one atomic per block
#pragma unroll
    for (int off = 32; off > 0; off >>= 1)
        acc += __shfl_down(acc, off, 64);

    __shared__ float wsum[NPTS / 64];
    const int wid  = k >> 6;
    const int lane = k & 63;
    if (lane == 0) wsum[wid] = acc;
    __syncthreads();
    if (k == 0) {
        float s = 0.0f;
#pragma unroll
        for (int w = 0; w < NPTS / 64; w++) s += wsum[w];
        atomicAdd(out, s * (1.0f / (384.0f * 384.0f * 384.0f)));
    }
}

extern "C" void kernel_launch(void* const* d_in, const int* in_sizes, int n_in,
                              void* d_out, int out_size, void* d_ws, size_t ws_size,
                              hipStream_t stream) {
    const float* student = (const float*)d_in[0];
    const float* teacher = (const float*)d_in[1];
    float* out = (float*)d_out;

    // workspace: P4 (NPTS*NPTS float4, 2.25 MiB) + W2 (NPTS*NPTS float2, 1.125 MiB)
    float4* P4 = (float4*)d_ws;
    float2* W2 = (float2*)(P4 + NPTS * NPTS);

    dim3 ggrid(NPTS / 32, NPTS / 32, 2);
    gram_pack_kernel<<<ggrid, 64, 0, stream>>>(student, teacher, P4, W2, out);

    dim3 mgrid(NPTS / TI, NPTS / JC, 1);
    rkd_angle_kernel<<<mgrid, NPTS, 0, stream>>>(P4, W2, out);
}

// Round 7
// 93.509 us; speedup vs baseline: 1.0749x; 1.0376x over previous
//
#include <hip/hip_runtime.h>

#define NPTS 384
#define DIMS 256
#define TI 6      // i-rows per block in main kernel
#define JC 24     // j-columns per block in main kernel

// ---------------------------------------------------------------------------
// Kernel A: fused Gram + diagonal + pack. grid (12,12,2): one 32x32 tile of
// one matrix (z: student/teacher) per 64-thread (1-wave) block, 4x4 micro.
// LDS k-major (transposed) so fragments come via ds_read_b128.
// While the k-loop runs, 64 "diag lanes" also accumulate ||e_i||^2 for the
// 32 i-rows (lanes 0..31, from AsT columns) and 32 j-rows (lanes 32..63,
// from BsT columns) -- so the block needs no cross-block diagonal data.
// Outputs, per matrix m (SPLIT arrays -- contiguous float4 stores; the
// interleaved-P4 variant measurably regressed ~4us via cross-XCD
// partial-line writes):
//   Pm[i][j] = { g_ii - g_ij , r_ij }  (float2; r_ij = 1/||e_i-e_j||, 0 on diag)
//   Wm[i][j] =   g_ij                  (float)
// Block (0,0,0) also zeroes out[0], replacing the hipMemsetAsync dispatch.
// ---------------------------------------------------------------------------
__global__ __launch_bounds__(64) void gram_pack_kernel(
        const float* __restrict__ Es, const float* __restrict__ Et,
        float2* __restrict__ Ps, float2* __restrict__ Pt,
        float* __restrict__ Ws, float* __restrict__ Wt,
        float* __restrict__ out) {
    const float* __restrict__ E = (blockIdx.z == 0) ? Es : Et;
    float2* __restrict__ P      = (blockIdx.z == 0) ? Ps : Pt;
    float* __restrict__ W       = (blockIdx.z == 0) ? Ws : Wt;

    if (blockIdx.x == 0 && blockIdx.y == 0 && blockIdx.z == 0 && threadIdx.x == 0)
        out[0] = 0.0f;

    __shared__ float AsT[32][36];
    __shared__ float BsT[32][36];
    __shared__ float dA[32];
    __shared__ float dB[32];

    const int t  = threadIdx.x;      // 0..63
    const int tx = t & 7;            // 0..7
    const int ty = t >> 3;           // 0..7
    const int i0 = blockIdx.x * 32;
    const int j0 = blockIdx.y * 32;

    // this thread's diagonal entry: column e of AsT (t<32) or BsT (t>=32)
    const int e = t & 31;
    const float* dsrc = (t < 32) ? &AsT[0][e] : &BsT[0][e];   // stride 36 floats
    float dsum = 0.0f;

    float acc[4][4] = {};

    for (int k0 = 0; k0 < DIMS; k0 += 32) {
        // stage 32x32 A/B tiles, transposed into k-major LDS
#pragma unroll
        for (int m = 0; m < 4; m++) {
            const int row = ty + 8 * m;
            float va[4], vb[4];
            *(float4*)va = *(const float4*)&E[(i0 + row) * DIMS + k0 + 4 * tx];
            *(float4*)vb = *(const float4*)&E[(j0 + row) * DIMS + k0 + 4 * tx];
#pragma unroll
            for (int q = 0; q < 4; q++) {
                AsT[4 * tx + q][row] = va[q];
                BsT[4 * tx + q][row] = vb[q];
            }
        }
        __syncthreads();
#pragma unroll
        for (int k = 0; k < 32; k++) {
            float a[4], b[4];
            *(float4*)a = *(const float4*)&AsT[k][4 * ty];
            *(float4*)b = *(const float4*)&BsT[k][4 * tx];
#pragma unroll
            for (int p = 0; p < 4; p++)
#pragma unroll
                for (int q = 0; q < 4; q++)
                    acc[p][q] = fmaf(a[p], b[q], acc[p][q]);
        }
        // diagonal partial for this chunk (lane-consecutive -> conflict-free)
#pragma unroll
        for (int k = 0; k < 32; k++) {
            float v = dsrc[k * 36];
            dsum = fmaf(v, v, dsum);
        }
        __syncthreads();
    }

    if (t < 32) dA[e] = dsum; else dB[e] = dsum;
    __syncthreads();

    // pack epilogue: 4x4 outputs per thread, contiguous float4 stores
#pragma unroll
    for (int p = 0; p < 4; p++) {
        const int i     = i0 + 4 * ty + p;
        const float dAv = dA[4 * ty + p];
        float2 prow[4];
        float  wrow[4];
#pragma unroll
        for (int q = 0; q < 4; q++) {
            const int j     = j0 + 4 * tx + q;
            const float g   = acc[p][q];
            const float dBv = dB[4 * tx + q];
            float v = fmaxf(dAv - 2.0f * g + dBv, 0.0f);
            float r = (i == j) ? 0.0f : 1.0f / fmaxf(sqrtf(v), 1e-12f);
            prow[q] = make_float2(dAv - g, r);
            wrow[q] = g;
        }
        *(float4*)&P[i * NPTS + j0 + 4 * tx]     = make_float4(prow[0].x, prow[0].y, prow[1].x, prow[1].y);
        *(float4*)&P[i * NPTS + j0 + 4 * tx + 2] = make_float4(prow[2].x, prow[2].y, prow[3].x, prow[3].y);
        *(float4*)&W[i * NPTS + j0 + 4 * tx]     = make_float4(wrow[0], wrow[1], wrow[2], wrow[3]);
    }
}

// ---------------------------------------------------------------------------
// Kernel B: main triple-loop reduction. NO LDS staging.
// Block: TI i-rows x JC j-cols, 384 threads (thread == k), grid 64x16.
// Per-(i,j) data comes from Ps/Pt via wave-uniform (scalarizable) float2
// loads; per-k state in VGPRs; G_jk values are coalesced dword loads.
// angle_ijk = r_ij * fma(r_ik, G_jk + (G_ii - G_ij), -r_ik*G_ik)
// huber(x)  = m*(x - 0.5m), m = min(|x|,1)   (branch-free, exact)
// ---------------------------------------------------------------------------
__global__ __launch_bounds__(NPTS) void rkd_angle_kernel(
        const float2* __restrict__ Ps, const float2* __restrict__ Pt,
        const float* __restrict__ Ws, const float* __restrict__ Wt,
        float* __restrict__ out) {
    const int k  = threadIdx.x;            // 0..383
    const int i0 = blockIdx.x * TI;
    const int j0 = blockIdx.y * JC;

    float rsk[TI], rtk[TI], nqs[TI], nqt[TI];
#pragma unroll
    for (int r = 0; r < TI; r++) {
        float2 ps = Ps[(i0 + r) * NPTS + k];   // coalesced 8B
        float2 pt = Pt[(i0 + r) * NPTS + k];
        float  ws = Ws[(i0 + r) * NPTS + k];   // coalesced 4B
        float  wt = Wt[(i0 + r) * NPTS + k];
        rsk[r] = ps.y;
        rtk[r] = pt.y;
        nqs[r] = -(ps.y * ws);
        nqt[r] = -(pt.y * wt);
    }

    float acc = 0.0f;
#pragma unroll 2
    for (int j = j0; j < j0 + JC; j++) {
        float ws = Ws[j * NPTS + k];           // coalesced per-lane g_jk
        float wt = Wt[j * NPTS + k];
#pragma unroll
        for (int r = 0; r < TI; r++) {
            float2 pjs = Ps[(i0 + r) * NPTS + j];   // wave-uniform
            float2 pjt = Pt[(i0 + r) * NPTS + j];   // wave-uniform
            float as = pjs.y * fmaf(rsk[r], ws + pjs.x, nqs[r]);
            float at = pjt.y * fmaf(rtk[r], wt + pjt.x, nqt[r]);
            float d  = as - at;
            float ad = fabsf(d);
            float m  = fminf(ad, 1.0f);
            acc = fmaf(m, fmaf(-0.5f, m, ad), acc);
        }
    }

    // wave reduce (64-wide)
#pragma unroll
    for (int off = 32; off > 0; off >>= 1)
        acc += __shfl_down(acc, off, 64);

    __shared__ float wsum[NPTS / 64];
    const int wid  = k >> 6;
    const int lane = k & 63;
    if (lane == 0) wsum[wid] = acc;
    __syncthreads();
    if (k == 0) {
        float s = 0.0f;
#pragma unroll
        for (int w = 0; w < NPTS / 64; w++) s += wsum[w];
        atomicAdd(out, s * (1.0f / (384.0f * 384.0f * 384.0f)));
    }
}

extern "C" void kernel_launch(void* const* d_in, const int* in_sizes, int n_in,
                              void* d_out, int out_size, void* d_ws, size_t ws_size,
                              hipStream_t stream) {
    const float* student = (const float*)d_in[0];
    const float* teacher = (const float*)d_in[1];
    float* out = (float*)d_out;

    // workspace layout (16B-aligned blocks):
    //   Ps, Pt : NPTS*NPTS float2  (1179648 B each)
    //   Ws, Wt : NPTS*NPTS float   ( 589824 B each)   total ~3.4 MiB
    float2* Ps = (float2*)d_ws;
    float2* Pt = Ps + NPTS * NPTS;
    float*  Ws = (float*)(Pt + NPTS * NPTS);
    float*  Wt = Ws + NPTS * NPTS;

    dim3 ggrid(NPTS / 32, NPTS / 32, 2);
    gram_pack_kernel<<<ggrid, 64, 0, stream>>>(student, teacher, Ps, Pt, Ws, Wt, out);

    dim3 mgrid(NPTS / TI, NPTS / JC, 1);
    rkd_angle_kernel<<<mgrid, NPTS, 0, stream>>>(Ps, Pt, Ws, Wt, out);
}